// Round 1
// baseline (367.063 us; speedup 1.0000x reference)
//
#include <hip/hip_runtime.h>
#include <math.h>

// Problem constants (reference: N=32, K=16, BINS=100, DIM=2, sample_size=100)
#define NBINS 100
#define NB    101   // BINS+1
#define NN    32
#define KDIM  16
#define NT    99    // sample_size-1

// ws layout (float offsets); total 30061 floats (~120 KB)
#define OFF_B    0        // Btil 101x101
#define OFF_S    10201    // s[b][j][d] 101*16*2
#define OFF_T    13433    // t[b][j][d]
#define OFF_Q    16665    // Q = C*U  32*16
#define OFF_C    17177    // c_j = sigma^-2 * mu_j  (16)
#define OFF_P    17193    // params: [0]=sigma_sq_inv [1]=-0.5/ls^2
#define OFF_XL   17197    // x_last 64
#define OFF_Y2   17261    // Y2[b][n][d] 101*64
#define OFF_XT   23725    // xt[t][n][d] 99*64

// ---------------------------------------------------------------- K1: setup
// Btil, x_last, G_C = C^T C -> Jacobi eig (f64) -> Q = C U, c_j, s projection.
__global__ __launch_bounds__(256) void k1_setup(
    const float* __restrict__ x0, const float* __restrict__ v,
    const float* __restrict__ sigma_in, const float* __restrict__ x0c_in,
    const float* __restrict__ ls_in, const float* __restrict__ Cq,
    float* __restrict__ ws)
{
  const int tid = threadIdx.x;
  const float ls = ls_in[0];
  const float inv2ls2 = -0.5f / (ls * ls);
  const float x0c = x0c_in[0];
  float sig = fmaxf(sigma_in[0], 0.05f);           // clip(sigma, 5/BINS)
  const float sigma_sq_inv = 1.0f / (sig * sig);

  // Btil = Bk + jitter*I  (block-diag: [0,0]=x0_c^2, [1:,1:]=RBF gram)
  for (int idx = tid; idx < NB * NB; idx += 256) {
    int i = idx / NB, j = idx % NB;
    float val;
    if (i == 0 || j == 0) {
      val = (i == 0 && j == 0) ? (x0c * x0c + 1e-5f) : 0.0f;
    } else {
      float dd = (float)(j - i) * 0.01f;           // centers[j-1]-centers[i-1]
      val = expf(dd * dd * inv2ls2);
      if (i == j) val += 1e-5f;
    }
    ws[OFF_B + idx] = val;
  }

  // x_last = x0 + 0.01 * sum_b v
  for (int idx = tid; idx < NN * 2; idx += 256) {
    float acc = 0.f;
    for (int p = 0; p < NBINS; ++p) acc += v[p * (NN * 2) + idx];
    ws[OFF_XL + idx] = x0[idx] + 0.01f * acc;
  }

  // --- G_C and Jacobi eigendecomposition (f64, parallel round-robin) ---
  __shared__ double A[16][16], At[16][16], V[16][16];
  __shared__ double csC[8], csS[8];
  __shared__ int prP[8], prQ[8];
  __shared__ float Qs[NN * KDIM];

  {
    int k1 = tid >> 4, k2 = tid & 15;
    double acc = 0.0;
    for (int n = 0; n < NN; ++n)
      acc += (double)Cq[n * 16 + k1] * (double)Cq[n * 16 + k2];
    A[k1][k2] = acc;
    V[k1][k2] = (k1 == k2) ? 1.0 : 0.0;
  }
  __syncthreads();

  for (int sweep = 0; sweep < 10; ++sweep)
  for (int r = 0; r < 15; ++r) {
    if (tid < 8) {
      int i = tid;
      int p = (i == 0) ? 0 : (1 + ((i - 1 + r) % 15));
      int q = 1 + ((14 - i + r) % 15);
      if (p > q) { int tt = p; p = q; q = tt; }
      prP[i] = p; prQ[i] = q;
      double app = A[p][p], aqq = A[q][q], apq = A[p][q];
      double c = 1.0, s = 0.0;
      if (fabs(apq) > 1e-300) {
        double th = (aqq - app) / (2.0 * apq);
        double t_ = ((th >= 0.0) ? 1.0 : -1.0) / (fabs(th) + sqrt(th * th + 1.0));
        c = 1.0 / sqrt(t_ * t_ + 1.0);
        s = t_ * c;
      }
      csC[i] = c; csS[i] = s;
    }
    __syncthreads();
    if (tid < 128) {                       // row phase: At = J^T A
      int i = tid >> 4, col = tid & 15;
      int p = prP[i], q = prQ[i];
      double c = csC[i], s = csS[i];
      double ap = A[p][col], aq = A[q][col];
      At[p][col] = c * ap - s * aq;
      At[q][col] = s * ap + c * aq;
    }
    __syncthreads();
    if (tid < 128) {                       // col phase: A = At J
      int i = tid >> 4, row = tid & 15;
      int p = prP[i], q = prQ[i];
      double c = csC[i], s = csS[i];
      double ap = At[row][p], aq = At[row][q];
      A[row][p] = c * ap - s * aq;
      A[row][q] = s * ap + c * aq;
    } else {                               // V = V J
      int t2 = tid - 128;
      int i = t2 >> 4, row = t2 & 15;
      int p = prP[i], q = prQ[i];
      double c = csC[i], s = csS[i];
      double vp = V[row][p], vq = V[row][q];
      V[row][p] = c * vp - s * vq;
      V[row][q] = s * vp + c * vq;
    }
    __syncthreads();
  }

  if (tid < 16) {
    double mu = A[tid][tid];
    if (mu < 0.0) mu = 0.0;
    ws[OFF_C + tid] = (float)((double)sigma_sq_inv * mu);
  }
  if (tid == 0) {
    ws[OFF_P + 0] = sigma_sq_inv;
    ws[OFF_P + 1] = inv2ls2;
  }
  // Q = C * U_C
  for (int idx = tid; idx < NN * KDIM; idx += 256) {
    int n = idx >> 4, j = idx & 15;
    double acc = 0.0;
    for (int k2 = 0; k2 < 16; ++k2) acc += (double)Cq[n * 16 + k2] * V[k2][j];
    Qs[idx] = (float)acc;
    ws[OFF_Q + idx] = (float)acc;
  }
  __syncthreads();

  // s[b][j][d] = sum_n Q[n][j] * x0v[b][n][d]
  for (int idx = tid; idx < NB * KDIM * 2; idx += 256) {
    int d = idx & 1, j = (idx >> 1) & 15, b = idx >> 5;
    const float* src = (b == 0) ? x0 : (v + (b - 1) * (NN * 2));
    float acc = 0.f;
    for (int n = 0; n < NN; ++n) acc += Qs[n * 16 + j] * src[n * 2 + d];
    ws[OFF_S + idx] = acc;
  }
}

// ------------------------------------------- K2: per-eigenvalue SPD solve
// Block j: M = I + c_j*Btil (f64 LDS), rhs = Btil*s_j, Cholesky, fwd+bwd solve.
__global__ __launch_bounds__(256) void k2_chol(float* __restrict__ ws)
{
  extern __shared__ double sm[];
  double* Ms   = sm;                 // 101*102
  double* sv   = Ms + NB * 102;      // 2*101
  double* rhs  = sv + 2 * NB;        // 2*101
  double* xs   = rhs + 2 * NB;       // 2*101
  double* sol  = xs + 2 * NB;        // 2*101
  double* scal = sol + 2 * NB;       // 2

  const int tid = threadIdx.x;
  const int j = blockIdx.x;
  const double c = (double)ws[OFF_C + j];

  for (int idx = tid; idx < NB * NB; idx += 256) {
    int i = idx / NB, col = idx % NB;
    Ms[i * 102 + col] = (double)ws[OFF_B + idx];
  }
  for (int idx = tid; idx < 2 * NB; idx += 256) {
    int d = idx / NB, b = idx % NB;
    sv[d * NB + b] = (double)ws[OFF_S + (b * 16 + j) * 2 + d];
  }
  __syncthreads();

  // rhs = Btil * s  (before scaling Ms in place)
  for (int idx = tid; idx < 2 * NB; idx += 256) {
    int d = idx / NB, b = idx % NB;
    double acc = 0.0;
    for (int bp = 0; bp < NB; ++bp) acc += Ms[b * 102 + bp] * sv[d * NB + bp];
    rhs[d * NB + b] = acc;
  }
  __syncthreads();

  // M = I + c*Btil
  for (int idx = tid; idx < NB * NB; idx += 256) {
    int i = idx / NB, col = idx % NB;
    double val = c * Ms[i * 102 + col];
    if (i == col) val += 1.0;
    Ms[i * 102 + col] = val;
  }
  __syncthreads();

  // In-place Cholesky (full-square trailing update keeps trailing symmetric)
  for (int k = 0; k < NB; ++k) {
    if (tid == 0) {
      double piv = sqrt(Ms[k * 102 + k]);
      Ms[k * 102 + k] = piv;
      scal[0] = 1.0 / piv;
    }
    __syncthreads();
    const int m = NB - 1 - k;
    const double is = scal[0];
    for (int t2 = tid; t2 < m; t2 += 256)
      Ms[(k + 1 + t2) * 102 + k] *= is;
    __syncthreads();
    for (int l = tid; l < m * m; l += 256) {
      int i = k + 1 + l / m;
      int col = k + 1 + l % m;
      Ms[i * 102 + col] -= Ms[i * 102 + k] * Ms[col * 102 + k];
    }
    __syncthreads();
  }

  // forward solve L y = rhs (both d at once)
  for (int i = 0; i < NB; ++i) {
    if (tid < 2) {
      double val = rhs[tid * NB + i] / Ms[i * 102 + i];
      xs[tid * NB + i] = val;
      scal[tid] = val;
    }
    __syncthreads();
    const int m = NB - 1 - i;
    for (int t2 = tid; t2 < 2 * m; t2 += 256) {
      int d = t2 & 1, r = i + 1 + (t2 >> 1);
      rhs[d * NB + r] -= Ms[r * 102 + i] * scal[d];
    }
    __syncthreads();
  }
  // backward solve L^T t = y
  for (int i = NB - 1; i >= 0; --i) {
    if (tid < 2) {
      double val = xs[tid * NB + i] / Ms[i * 102 + i];
      sol[tid * NB + i] = val;
      scal[tid] = val;
    }
    __syncthreads();
    for (int t2 = tid; t2 < 2 * i; t2 += 256) {
      int d = t2 & 1, r = t2 >> 1;
      xs[d * NB + r] -= Ms[i * 102 + r] * scal[d];
    }
    __syncthreads();
  }

  for (int idx = tid; idx < 2 * NB; idx += 256) {
    int d = idx / NB, b = idx % NB;
    ws[OFF_T + (b * 16 + j) * 2 + d] = (float)sol[d * NB + b];
  }
}

// ------------------------------ K3: y = s^-2 x - s^-4 Q t ; Y2 = C C^T y
__global__ __launch_bounds__(64) void k3_y2(
    const float* __restrict__ x0, const float* __restrict__ v,
    const float* __restrict__ Cq, float* __restrict__ ws)
{
  const int b = blockIdx.x, tid = threadIdx.x;
  __shared__ float tv[32], yv[64], av[32];
  if (tid < 32) tv[tid] = ws[OFF_T + b * 32 + tid];
  __syncthreads();
  const float sinv = ws[OFF_P + 0];
  {
    int n = tid >> 1, d = tid & 1;
    float acc = 0.f;
    for (int j = 0; j < 16; ++j) acc += ws[OFF_Q + n * 16 + j] * tv[j * 2 + d];
    float xv = (b == 0) ? x0[tid] : v[(b - 1) * 64 + tid];
    yv[tid] = sinv * xv - sinv * sinv * acc;
  }
  __syncthreads();
  if (tid < 32) {
    int k = tid >> 1, d = tid & 1;
    float acc = 0.f;
    for (int n = 0; n < 32; ++n) acc += Cq[n * 16 + k] * yv[n * 2 + d];
    av[tid] = acc;
  }
  __syncthreads();
  {
    int n = tid >> 1, d = tid & 1;
    float acc = 0.f;
    for (int k = 0; k < 16; ++k) acc += Cq[n * 16 + k] * av[k * 2 + d];
    ws[OFF_Y2 + b * 64 + tid] = acc;
  }
}

// ------------------------- K4: pred_v = B_cross^T Y2 ; xt = x_last + trel*pv
__global__ __launch_bounds__(64) void k4_xt(float* __restrict__ ws)
{
  const int t = blockIdx.x, tid = threadIdx.x;
  __shared__ float Bc[NBINS];
  const float inv2ls2 = ws[OFF_P + 1];
  const float trel = (float)t * (1.0f / 99.0f);   // ts[t]-1
  const float tst = 1.0f + trel;
  for (int p = tid; p < NBINS; p += 64) {
    float dd = tst - ((float)p + 0.5f) * 0.01f;
    Bc[p] = expf(dd * dd * inv2ls2);
  }
  __syncthreads();
  float acc = 0.f;
  for (int p = 0; p < NBINS; ++p) acc += Bc[p] * ws[OFF_Y2 + (p + 1) * 64 + tid];
  ws[OFF_XT + t * 64 + tid] = ws[OFF_XL + tid] + trel * acc;
}

// --------------------------------------------- K5: intensity integral
__global__ __launch_bounds__(256) void k5_out(
    const float* __restrict__ beta, const float* __restrict__ ws,
    float* __restrict__ out)
{
  __shared__ float sxt[NT * 64];
  const int tid = threadIdx.x;
  for (int i = tid; i < NT * 64; i += 256) sxt[i] = ws[OFF_XT + i];
  __syncthreads();
  const int pair = blockIdx.x * 256 + tid;
  const int i = pair >> 5, j = pair & 31;
  const float bsum = beta[i] + beta[j];
  float acc = 0.f;
  for (int t = 0; t < NT; ++t) {
    float dx = sxt[t * 64 + i * 2]     - sxt[t * 64 + j * 2];
    float dy = sxt[t * 64 + i * 2 + 1] - sxt[t * 64 + j * 2 + 1];
    float sq = fmaxf(dx * dx + dy * dy, 1e-12f);
    acc += expf(bsum - sqrtf(sq));
  }
  out[pair] = acc * (1.0f / 99.0f);
}

extern "C" void kernel_launch(void* const* d_in, const int* in_sizes, int n_in,
                              void* d_out, int out_size, void* d_ws, size_t ws_size,
                              hipStream_t stream) {
  const float* x0    = (const float*)d_in[0];
  const float* v     = (const float*)d_in[1];
  const float* beta  = (const float*)d_in[2];
  const float* sigma = (const float*)d_in[3];
  const float* x0c   = (const float*)d_in[4];
  const float* ls    = (const float*)d_in[5];
  const float* Cq    = (const float*)d_in[6];
  // d_in[7] = sample_size (always 100 per setup_inputs; NT=99 hardcoded)
  float* out = (float*)d_out;
  float* ws  = (float*)d_ws;

  k1_setup<<<1, 256, 0, stream>>>(x0, v, sigma, x0c, ls, Cq, ws);
  const size_t smem2 = (size_t)(NB * 102 + 8 * NB + 2) * sizeof(double); // ~89 KB
  k2_chol<<<16, 256, smem2, stream>>>(ws);
  k3_y2<<<NB, 64, 0, stream>>>(x0, v, Cq, ws);
  k4_xt<<<NT, 64, 0, stream>>>(ws);
  k5_out<<<4, 256, 0, stream>>>(beta, ws, out);
}